// Round 1
// baseline (3686.501 us; speedup 1.0000x reference)
//
#include <hip/hip_runtime.h>
#include <hip/hip_bf16.h>
#include <math.h>

#define IGNORE_INDEX (-100)

typedef __attribute__((ext_vector_type(8))) __bf16 bf16x8;
typedef __attribute__((ext_vector_type(8))) unsigned short u16x8;
typedef __attribute__((ext_vector_type(4))) float f32x4;

static constexpr int B_ = 4, S_ = 2048, H_ = 4096, V_ = 32000;
static constexpr int N_ = B_ * (S_ - 1);      // 8188 rows after causal shift
static constexpr int NPAD = 8192;             // padded rows
static constexpr int BM = 128, BN = 128, BK = 32;
static constexpr int NVB = V_ / BN;           // 250 v-blocks
static constexpr int NRB = NPAD / BM;         // 64 row-blocks

__device__ __forceinline__ unsigned short f2bf(float f) {
    unsigned int u = __float_as_uint(f);
    unsigned int r = (u + 0x7FFFu + ((u >> 16) & 1u)) >> 16;
    return (unsigned short)r;
}

__device__ __forceinline__ bf16x8 as_bf16x8(u16x8 v) {
    return __builtin_bit_cast(bf16x8, v);
}

// ---------- convert hidden_states (causal-shifted) to bf16, pad to NPAD rows ----------
__global__ void conv_hs_kernel(const float* __restrict__ hs, unsigned short* __restrict__ A) {
    int idx = blockIdx.x * blockDim.x + threadIdx.x;   // one thread per 8 elements
    const int W8 = H_ / 8;                             // 512
    if (idx >= NPAD * W8) return;
    int row = idx / W8;
    int h8  = (idx - row * W8) * 8;
    u16x8 out;
    if (row < N_) {
        int b = row / (S_ - 1);
        int s = row - b * (S_ - 1);
        const float* src = hs + (size_t)(b * S_ + s) * H_ + h8;
        f32x4 v0 = *(const f32x4*)(src);
        f32x4 v1 = *(const f32x4*)(src + 4);
        out[0] = f2bf(v0.x); out[1] = f2bf(v0.y); out[2] = f2bf(v0.z); out[3] = f2bf(v0.w);
        out[4] = f2bf(v1.x); out[5] = f2bf(v1.y); out[6] = f2bf(v1.z); out[7] = f2bf(v1.w);
    } else {
        out = (u16x8)0;
    }
    *(u16x8*)(A + (size_t)row * H_ + h8) = out;
}

// ---------- convert lm_head weight to bf16 ----------
__global__ void conv_w_kernel(const float* __restrict__ w, unsigned short* __restrict__ Wb) {
    int idx = blockIdx.x * blockDim.x + threadIdx.x;   // one thread per 8 elements
    const int W8 = H_ / 8;
    if (idx >= V_ * W8) return;
    int row = idx / W8;
    int h8  = (idx - row * W8) * 8;
    const float* src = w + (size_t)row * H_ + h8;
    f32x4 v0 = *(const f32x4*)(src);
    f32x4 v1 = *(const f32x4*)(src + 4);
    u16x8 out;
    out[0] = f2bf(v0.x); out[1] = f2bf(v0.y); out[2] = f2bf(v0.z); out[3] = f2bf(v0.w);
    out[4] = f2bf(v1.x); out[5] = f2bf(v1.y); out[6] = f2bf(v1.z); out[7] = f2bf(v1.w);
    *(u16x8*)(Wb + (size_t)row * H_ + h8) = out;
}

// ---------- GEMM + fused partial logsumexp ----------
// grid (NVB, NRB), 256 threads (4 waves, 2x2 of 64x64 sub-tiles)
__global__ __launch_bounds__(256) void gemm_lse_kernel(
        const unsigned short* __restrict__ A,   // [NPAD][H] bf16
        const unsigned short* __restrict__ Wb,  // [V][H] bf16
        const int* __restrict__ labels,         // [B][S]
        float* __restrict__ partial_m,          // [NPAD][NVB]
        float* __restrict__ partial_s,          // [NPAD][NVB]
        float* __restrict__ label_logit)        // [NPAD]
{
    __shared__ unsigned short As[BM][BK];   // 8 KB
    __shared__ unsigned short Bs[BN][BK];   // 8 KB
    __shared__ float red_m[2][BM];
    __shared__ float red_s[2][BM];

    const int vb = blockIdx.x;
    const int rb = blockIdx.y;
    const int tid  = threadIdx.x;
    const int lane = tid & 63;
    const int wave = tid >> 6;
    const int wr = wave >> 1;      // 0..1 row half
    const int wc = wave & 1;       // 0..1 col half

    const unsigned short* Abase = A  + (size_t)(rb * BM) * H_;
    const unsigned short* Bbase = Wb + (size_t)(vb * BN) * H_;

    f32x4 acc[4][4] = {};

    // staging addresses: wave w, issue i covers rows w*32+i*16 .. +16, lane l -> row +(l>>2), col (l&3)*8
    const int st_r = (lane >> 2);
    const int st_c = (lane & 3) * 8;

    for (int k0 = 0; k0 < H_; k0 += BK) {
        __syncthreads();
        #pragma unroll
        for (int i = 0; i < 2; ++i) {
            int r = wave * 32 + i * 16;
            __builtin_amdgcn_global_load_lds(
                (const __attribute__((address_space(1))) unsigned int*)(Abase + (size_t)(r + st_r) * H_ + k0 + st_c),
                (__attribute__((address_space(3))) unsigned int*)(&As[r][0]),
                16, 0, 0);
            __builtin_amdgcn_global_load_lds(
                (const __attribute__((address_space(1))) unsigned int*)(Bbase + (size_t)(r + st_r) * H_ + k0 + st_c),
                (__attribute__((address_space(3))) unsigned int*)(&Bs[r][0]),
                16, 0, 0);
        }
        __syncthreads();

        const int kr = (lane >> 4) * 8;
        u16x8 af[4], bfv[4];
        #pragma unroll
        for (int m = 0; m < 4; ++m)
            af[m] = *(const u16x8*)(&As[wr * 64 + m * 16 + (lane & 15)][kr]);
        #pragma unroll
        for (int n = 0; n < 4; ++n)
            bfv[n] = *(const u16x8*)(&Bs[wc * 64 + n * 16 + (lane & 15)][kr]);

        #pragma unroll
        for (int m = 0; m < 4; ++m)
            #pragma unroll
            for (int n = 0; n < 4; ++n)
                acc[m][n] = __builtin_amdgcn_mfma_f32_16x16x32_bf16(
                    as_bf16x8(af[m]), as_bf16x8(bfv[n]), acc[m][n], 0, 0, 0);
    }

    // ---------- epilogue: per-row max & sum-exp over this 128-col tile ----------
    __syncthreads();

    #pragma unroll
    for (int m = 0; m < 4; ++m) {
        #pragma unroll
        for (int q = 0; q < 4; ++q) {
            float mx = acc[m][0][q];
            mx = fmaxf(mx, acc[m][1][q]);
            mx = fmaxf(mx, acc[m][2][q]);
            mx = fmaxf(mx, acc[m][3][q]);
            #pragma unroll
            for (int d = 1; d < 16; d <<= 1)
                mx = fmaxf(mx, __shfl_xor(mx, d, 64));
            float ss = __expf(acc[m][0][q] - mx) + __expf(acc[m][1][q] - mx)
                     + __expf(acc[m][2][q] - mx) + __expf(acc[m][3][q] - mx);
            #pragma unroll
            for (int d = 1; d < 16; d <<= 1)
                ss += __shfl_xor(ss, d, 64);
            int rloc = wr * 64 + m * 16 + (lane >> 4) * 4 + q;
            if ((lane & 15) == 0) {
                red_m[wc][rloc] = mx;
                red_s[wc][rloc] = ss;
            }
        }
    }
    __syncthreads();

    if (tid < BM) {
        float m0 = red_m[0][tid], m1 = red_m[1][tid];
        float s0 = red_s[0][tid], s1 = red_s[1][tid];
        float mm = fmaxf(m0, m1);
        float ss = s0 * __expf(m0 - mm) + s1 * __expf(m1 - mm);
        int rowg = rb * BM + tid;
        partial_m[(size_t)rowg * NVB + vb] = mm;
        partial_s[(size_t)rowg * NVB + vb] = ss;
    }

    // ---------- capture the label logit if it falls in this tile ----------
    #pragma unroll
    for (int m = 0; m < 4; ++m) {
        #pragma unroll
        for (int q = 0; q < 4; ++q) {
            int rowg = rb * BM + wr * 64 + m * 16 + (lane >> 4) * 4 + q;
            if (rowg < N_) {
                int b = rowg / (S_ - 1);
                int s = rowg - b * (S_ - 1);
                int lbl = labels[b * S_ + s + 1];
                int c = lbl - (vb * BN + wc * 64);
                if (c >= 0 && c < 64 && (c & 15) == (lane & 15)) {
                    int nsel = c >> 4;
                    float val;
                    // static indexing only (runtime-indexed ext_vector -> scratch)
                    if (nsel == 0)      val = acc[m][0][q];
                    else if (nsel == 1) val = acc[m][1][q];
                    else if (nsel == 2) val = acc[m][2][q];
                    else                val = acc[m][3][q];
                    label_logit[rowg] = val;
                }
            }
        }
    }
}

// ---------- per-row combine of partials -> nll ----------
__global__ void row_nll_kernel(const float* __restrict__ partial_m,
                               const float* __restrict__ partial_s,
                               const float* __restrict__ label_logit,
                               const int* __restrict__ labels,
                               float* __restrict__ nll)
{
    int row = blockIdx.x * blockDim.x + threadIdx.x;
    if (row >= N_) return;
    const float* pm = partial_m + (size_t)row * NVB;
    const float* ps = partial_s + (size_t)row * NVB;
    float mm = -INFINITY;
    for (int j = 0; j < NVB; ++j) mm = fmaxf(mm, pm[j]);
    float ss = 0.f;
    for (int j = 0; j < NVB; ++j) ss += ps[j] * expf(pm[j] - mm);
    float lse = mm + logf(ss);
    int b = row / (S_ - 1);
    int s = row - b * (S_ - 1);
    int lbl = labels[b * S_ + s + 1];
    float out = 0.f;
    if (lbl != IGNORE_INDEX) out = lse - label_logit[row];
    nll[row] = out;
}

// ---------- final mean over valid rows ----------
__global__ void final_reduce_kernel(const float* __restrict__ nll,
                                    const int* __restrict__ labels,
                                    float* __restrict__ out)
{
    __shared__ float s_sum[256];
    __shared__ float s_cnt[256];
    int tid = threadIdx.x;
    float sum = 0.f, cnt = 0.f;
    for (int row = tid; row < N_; row += 256) {
        int b = row / (S_ - 1);
        int s = row - b * (S_ - 1);
        int lbl = labels[b * S_ + s + 1];
        if (lbl != IGNORE_INDEX) { sum += nll[row]; cnt += 1.f; }
    }
    s_sum[tid] = sum; s_cnt[tid] = cnt;
    __syncthreads();
    for (int d = 128; d > 0; d >>= 1) {
        if (tid < d) { s_sum[tid] += s_sum[tid + d]; s_cnt[tid] += s_cnt[tid + d]; }
        __syncthreads();
    }
    if (tid == 0) out[0] = s_sum[0] / fmaxf(s_cnt[0], 1.f);
}

extern "C" void kernel_launch(void* const* d_in, const int* in_sizes, int n_in,
                              void* d_out, int out_size, void* d_ws, size_t ws_size,
                              hipStream_t stream) {
    const float* hs  = (const float*)d_in[0];
    const float* w   = (const float*)d_in[1];
    const int*   lbl = (const int*)d_in[2];
    float* out = (float*)d_out;

    char* ws = (char*)d_ws;
    size_t off = 0;
    unsigned short* A_bf16 = (unsigned short*)(ws + off); off += (size_t)NPAD * H_ * 2;           // 64 MB
    unsigned short* W_bf16 = (unsigned short*)(ws + off); off += (size_t)V_ * H_ * 2;             // 250 MB
    float* partial_m   = (float*)(ws + off); off += (size_t)NPAD * NVB * 4;                       // 8 MB
    float* partial_s   = (float*)(ws + off); off += (size_t)NPAD * NVB * 4;                       // 8 MB
    float* label_logit = (float*)(ws + off); off += (size_t)NPAD * 4;
    float* nll         = (float*)(ws + off); off += (size_t)NPAD * 4;

    {
        int total = NPAD * (H_ / 8);
        conv_hs_kernel<<<(total + 255) / 256, 256, 0, stream>>>(hs, A_bf16);
    }
    {
        int total = V_ * (H_ / 8);
        conv_w_kernel<<<(total + 255) / 256, 256, 0, stream>>>(w, W_bf16);
    }
    {
        dim3 grid(NVB, NRB);
        gemm_lse_kernel<<<grid, 256, 0, stream>>>(A_bf16, W_bf16, lbl,
                                                  partial_m, partial_s, label_logit);
    }
    row_nll_kernel<<<(N_ + 255) / 256, 256, 0, stream>>>(partial_m, partial_s, label_logit, lbl, nll);
    final_reduce_kernel<<<1, 256, 0, stream>>>(nll, lbl, out);
}

// Round 2
// 2315.702 us; speedup vs baseline: 1.5920x; 1.5920x over previous
//
#include <hip/hip_runtime.h>
#include <hip/hip_bf16.h>
#include <math.h>

#define IGNORE_INDEX (-100)

typedef __attribute__((ext_vector_type(8))) __bf16 bf16x8;
typedef __attribute__((ext_vector_type(8))) unsigned short u16x8;
typedef __attribute__((ext_vector_type(4))) float f32x4;

static constexpr int B_ = 4, S_ = 2048, H_ = 4096, V_ = 32000;
static constexpr int N_ = B_ * (S_ - 1);      // 8188 rows after causal shift
static constexpr int NPAD = 8192;             // padded rows
static constexpr int BM = 256, BN = 256, BK = 64;
static constexpr int NVB = V_ / BN;           // 125 v-blocks
static constexpr int NRB = NPAD / BM;         // 32 row-blocks
static constexpr int NKT = H_ / BK;           // 64 K-tiles
static constexpr int NWG = NVB * NRB;         // 4000 blocks

__device__ __forceinline__ unsigned short f2bf(float f) {
    unsigned int u = __float_as_uint(f);
    unsigned int r = (u + 0x7FFFu + ((u >> 16) & 1u)) >> 16;
    return (unsigned short)r;
}

__device__ __forceinline__ bf16x8 as_bf16x8(u16x8 v) {
    return __builtin_bit_cast(bf16x8, v);
}

__device__ __forceinline__ void gload16(const unsigned short* src, unsigned short* ldst) {
    __builtin_amdgcn_global_load_lds(
        (const __attribute__((address_space(1))) unsigned int*)src,
        (__attribute__((address_space(3))) unsigned int*)ldst, 16, 0, 0);
}

// ---------- convert hidden_states (causal-shifted) to bf16, pad to NPAD rows ----------
__global__ void conv_hs_kernel(const float* __restrict__ hs, unsigned short* __restrict__ A) {
    int idx = blockIdx.x * blockDim.x + threadIdx.x;   // one thread per 8 elements
    const int W8 = H_ / 8;                             // 512
    if (idx >= NPAD * W8) return;
    int row = idx / W8;
    int h8  = (idx - row * W8) * 8;
    u16x8 out;
    if (row < N_) {
        int b = row / (S_ - 1);
        int s = row - b * (S_ - 1);
        const float* src = hs + (size_t)(b * S_ + s) * H_ + h8;
        f32x4 v0 = *(const f32x4*)(src);
        f32x4 v1 = *(const f32x4*)(src + 4);
        out[0] = f2bf(v0.x); out[1] = f2bf(v0.y); out[2] = f2bf(v0.z); out[3] = f2bf(v0.w);
        out[4] = f2bf(v1.x); out[5] = f2bf(v1.y); out[6] = f2bf(v1.z); out[7] = f2bf(v1.w);
    } else {
        out = (u16x8)0;
    }
    *(u16x8*)(A + (size_t)row * H_ + h8) = out;
}

// ---------- convert lm_head weight to bf16 ----------
__global__ void conv_w_kernel(const float* __restrict__ w, unsigned short* __restrict__ Wb) {
    int idx = blockIdx.x * blockDim.x + threadIdx.x;   // one thread per 8 elements
    const int W8 = H_ / 8;
    if (idx >= V_ * W8) return;
    int row = idx / W8;
    int h8  = (idx - row * W8) * 8;
    const float* src = w + (size_t)row * H_ + h8;
    f32x4 v0 = *(const f32x4*)(src);
    f32x4 v1 = *(const f32x4*)(src + 4);
    u16x8 out;
    out[0] = f2bf(v0.x); out[1] = f2bf(v0.y); out[2] = f2bf(v0.z); out[3] = f2bf(v0.w);
    out[4] = f2bf(v1.x); out[5] = f2bf(v1.y); out[6] = f2bf(v1.z); out[7] = f2bf(v1.w);
    *(u16x8*)(Wb + (size_t)row * H_ + h8) = out;
}

// ---------- 256x256 8-wave phase-split GEMM + fused partial logsumexp ----------
// LDS layout per buffer per matrix: logical [256 rows][64 cols] bf16, row stride 128 B,
// physical byte = logical byte ^ ((bit9)<<5)  (st_16x32 swizzle).
__global__ __launch_bounds__(512, 2) void gemm_lse_kernel(
        const unsigned short* __restrict__ A,   // [NPAD][H] bf16
        const unsigned short* __restrict__ Wb,  // [V][H] bf16
        const int* __restrict__ labels,         // [B][S]
        float* __restrict__ partial_m,          // [NPAD][NVB]
        float* __restrict__ partial_s,          // [NPAD][NVB]
        float* __restrict__ label_logit)        // [NPAD]
{
    __shared__ unsigned short lds[2][2][BM * BK];   // [buf][A=0/B=1], 128 KiB total

    const int tid  = threadIdx.x;
    const int lane = tid & 63;
    const int wid  = tid >> 6;
    const int wr   = wid >> 2;      // 0..1: row half (also: which A-half this wave stages)
    const int wc   = wid & 3;       // 0..3: col quarter
    const int aw   = wid & 3;       // index within A-staging group
    const int lq   = lane & 15;
    const int lr   = lane >> 4;

    // bijective XCD swizzle (NWG % 8 == 0): each XCD gets 500 consecutive tiles
    int lin = blockIdx.x;
    int swz = (lin & 7) * (NWG / 8) + (lin >> 3);
    const int rb = swz / NVB;
    const int vb = swz - rb * NVB;

    const unsigned short* Abase = A  + (size_t)rb * BM * H_;
    const unsigned short* Bbase = Wb + (size_t)vb * BN * H_;

    // ds_read physical byte offsets (kk=0; kk=1 adds +64, swizzle bit unaffected)
    int pA[8], pB[4];
    #pragma unroll
    for (int m = 0; m < 8; ++m) {
        int r = wr * 128 + m * 16 + lq;
        pA[m] = (r * 128 + lr * 16) ^ (((r >> 2) & 1) << 5);
    }
    #pragma unroll
    for (int n = 0; n < 4; ++n) {
        int r = wc * 64 + n * 16 + lq;
        pB[n] = (r * 128 + lr * 16) ^ (((r >> 2) & 1) << 5);
    }

    // staging: physical dest is linear; per-lane global source is inverse-swizzled.
    // B: 4 slots = (half h, pass p); dest base = h*16384 + p*8192 + wid*1024
    int rowB[4], colB[4];
    #pragma unroll
    for (int s = 0; s < 4; ++s) {
        int q = (s >> 1) * 16384 + (s & 1) * 8192 + tid * 16;   // physical
        int b = q ^ (((q >> 9) & 1) << 5);                      // logical
        rowB[s] = b >> 7;
        colB[s] = (b & 127) >> 1;
    }
    // A: wave-split — waves with wr=0 stage rows 0..127, wr=1 stage 128..255; 4 passes each
    int rowA[4], colA[4];
    #pragma unroll
    for (int p = 0; p < 4; ++p) {
        int q = wr * 16384 + (aw * 4 + p) * 1024 + lane * 16;
        int b = q ^ (((q >> 9) & 1) << 5);
        rowA[p] = b >> 7;
        colA[p] = (b & 127) >> 1;
    }

    f32x4 acc[8][4] = {};

    // ---------- prologue: stage K-tile 0 into buf0 ----------
    {
        unsigned short* sA = &lds[0][0][0];
        unsigned short* sB = &lds[0][1][0];
        #pragma unroll
        for (int s = 0; s < 4; ++s)
            gload16(Bbase + (size_t)rowB[s] * H_ + colB[s],
                    (unsigned short*)((char*)sB + (s >> 1) * 16384 + (s & 1) * 8192 + wid * 1024));
        #pragma unroll
        for (int p = 0; p < 4; ++p)
            gload16(Abase + (size_t)rowA[p] * H_ + colA[p],
                    (unsigned short*)((char*)sA + wr * 16384 + (aw * 4 + p) * 1024));
    }
    asm volatile("s_waitcnt vmcnt(0)" ::: "memory");
    __builtin_amdgcn_s_barrier();

#define RD(tile, off) (*(const u16x8*)((const char*)(tile) + (off)))
#define MF(af, bf, c4) __builtin_amdgcn_mfma_f32_16x16x32_bf16(as_bf16x8(af), as_bf16x8(bf), c4, 0, 0, 0)
#define MFMA16(MO) do { \
    acc[MO+0][0]=MF(a0,b0,acc[MO+0][0]); acc[MO+0][1]=MF(a0,b1,acc[MO+0][1]); \
    acc[MO+0][2]=MF(a0,b2,acc[MO+0][2]); acc[MO+0][3]=MF(a0,b3,acc[MO+0][3]); \
    acc[MO+1][0]=MF(a1,b0,acc[MO+1][0]); acc[MO+1][1]=MF(a1,b1,acc[MO+1][1]); \
    acc[MO+1][2]=MF(a1,b2,acc[MO+1][2]); acc[MO+1][3]=MF(a1,b3,acc[MO+1][3]); \
    acc[MO+2][0]=MF(a2,b0,acc[MO+2][0]); acc[MO+2][1]=MF(a2,b1,acc[MO+2][1]); \
    acc[MO+2][2]=MF(a2,b2,acc[MO+2][2]); acc[MO+2][3]=MF(a2,b3,acc[MO+2][3]); \
    acc[MO+3][0]=MF(a3,b0,acc[MO+3][0]); acc[MO+3][1]=MF(a3,b1,acc[MO+3][1]); \
    acc[MO+3][2]=MF(a3,b2,acc[MO+3][2]); acc[MO+3][3]=MF(a3,b3,acc[MO+3][3]); \
} while (0)
#define PHASE_MID() do { \
    __builtin_amdgcn_s_barrier(); \
    asm volatile("s_waitcnt lgkmcnt(0)" ::: "memory"); \
    __builtin_amdgcn_sched_barrier(0); \
    __builtin_amdgcn_s_setprio(1); } while (0)
#define PHASE_END() do { \
    __builtin_amdgcn_s_setprio(0); \
    __builtin_amdgcn_s_barrier(); } while (0)

    for (int T = 0; T < NKT; ++T) {
        const int c = T & 1;
        const unsigned short* tA = &lds[c][0][0];
        const unsigned short* tB = &lds[c][1][0];
        unsigned short* sA = &lds[c ^ 1][0][0];
        unsigned short* sB = &lds[c ^ 1][1][0];
        const int kn = (T + 1) * BK;
        const bool pre = (T + 1 < NKT);
        u16x8 a0, a1, a2, a3, b0, b1, b2, b3;

        // ---- phase 0: stage B-top(T+1); read A m0-3 kk0 + B kk0; MFMA upper kk0
        if (pre) {
            gload16(Bbase + (size_t)rowB[0] * H_ + kn + colB[0],
                    (unsigned short*)((char*)sB + 0 * 8192 + wid * 1024));
            gload16(Bbase + (size_t)rowB[1] * H_ + kn + colB[1],
                    (unsigned short*)((char*)sB + 1 * 8192 + wid * 1024));
        }
        a0 = RD(tA, pA[0]); a1 = RD(tA, pA[1]); a2 = RD(tA, pA[2]); a3 = RD(tA, pA[3]);
        b0 = RD(tB, pB[0]); b1 = RD(tB, pB[1]); b2 = RD(tB, pB[2]); b3 = RD(tB, pB[3]);
        PHASE_MID(); MFMA16(0); PHASE_END();

        // ---- phase 1: stage B-bot(T+1); read A m4-7 kk0; MFMA lower kk0
        if (pre) {
            gload16(Bbase + (size_t)rowB[2] * H_ + kn + colB[2],
                    (unsigned short*)((char*)sB + 16384 + 0 * 8192 + wid * 1024));
            gload16(Bbase + (size_t)rowB[3] * H_ + kn + colB[3],
                    (unsigned short*)((char*)sB + 16384 + 1 * 8192 + wid * 1024));
        }
        a0 = RD(tA, pA[4]); a1 = RD(tA, pA[5]); a2 = RD(tA, pA[6]); a3 = RD(tA, pA[7]);
        PHASE_MID(); MFMA16(4); PHASE_END();

        // ---- phase 2: stage A(T+1) (wave-split, both halves); read A m0-3 kk1 + B kk1
        if (pre) {
            #pragma unroll
            for (int p = 0; p < 4; ++p)
                gload16(Abase + (size_t)rowA[p] * H_ + kn + colA[p],
                        (unsigned short*)((char*)sA + wr * 16384 + (aw * 4 + p) * 1024));
        }
        a0 = RD(tA, pA[0] + 64); a1 = RD(tA, pA[1] + 64); a2 = RD(tA, pA[2] + 64); a3 = RD(tA, pA[3] + 64);
        b0 = RD(tB, pB[0] + 64); b1 = RD(tB, pB[1] + 64); b2 = RD(tB, pB[2] + 64); b3 = RD(tB, pB[3] + 64);
        PHASE_MID(); MFMA16(0); PHASE_END();

        // ---- phase 3: read A m4-7 kk1; MFMA lower kk1; drain stages for next tile
        a0 = RD(tA, pA[4] + 64); a1 = RD(tA, pA[5] + 64); a2 = RD(tA, pA[6] + 64); a3 = RD(tA, pA[7] + 64);
        PHASE_MID(); MFMA16(4);
        __builtin_amdgcn_s_setprio(0);
        asm volatile("s_waitcnt vmcnt(0)" ::: "memory");
        __builtin_amdgcn_s_barrier();
    }

    // ---------- epilogue: per-row max & sum-exp over this 256-col tile ----------
    __syncthreads();
    float* red_m = (float*)&lds[0][0][0];   // [4][256]
    float* red_s = red_m + 1024;            // [4][256]

    #pragma unroll
    for (int m = 0; m < 8; ++m) {
        #pragma unroll
        for (int q = 0; q < 4; ++q) {
            float mx = fmaxf(fmaxf(acc[m][0][q], acc[m][1][q]), fmaxf(acc[m][2][q], acc[m][3][q]));
            #pragma unroll
            for (int d = 1; d < 16; d <<= 1) mx = fmaxf(mx, __shfl_xor(mx, d, 64));
            float ss = __expf(acc[m][0][q] - mx) + __expf(acc[m][1][q] - mx)
                     + __expf(acc[m][2][q] - mx) + __expf(acc[m][3][q] - mx);
            #pragma unroll
            for (int d = 1; d < 16; d <<= 1) ss += __shfl_xor(ss, d, 64);
            if (lq == 0) {
                int rloc = wr * 128 + m * 16 + lr * 4 + q;
                red_m[wc * 256 + rloc] = mx;
                red_s[wc * 256 + rloc] = ss;
            }
        }
    }
    __syncthreads();
    if (tid < 256) {
        float m0 = red_m[tid], m1 = red_m[256 + tid], m2 = red_m[512 + tid], m3 = red_m[768 + tid];
        float s0 = red_s[tid], s1 = red_s[256 + tid], s2 = red_s[512 + tid], s3 = red_s[768 + tid];
        float mm = fmaxf(fmaxf(m0, m1), fmaxf(m2, m3));
        float ss = s0 * __expf(m0 - mm) + s1 * __expf(m1 - mm)
                 + s2 * __expf(m2 - mm) + s3 * __expf(m3 - mm);
        int rowg = rb * BM + tid;
        partial_m[(size_t)rowg * NVB + vb] = mm;
        partial_s[(size_t)rowg * NVB + vb] = ss;
    }

    // ---------- capture the label logit if it falls in this tile ----------
    #pragma unroll
    for (int m = 0; m < 8; ++m) {
        #pragma unroll
        for (int q = 0; q < 4; ++q) {
            int rowg = rb * BM + wr * 128 + m * 16 + lr * 4 + q;
            if (rowg < N_) {
                int bb = rowg / (S_ - 1);
                int s = rowg - bb * (S_ - 1);
                int lbl = labels[bb * S_ + s + 1];
                int ccol = lbl - (vb * BN + wc * 64);
                if (ccol >= 0 && ccol < 64 && (ccol & 15) == lq) {
                    int nsel = ccol >> 4;
                    float val;
                    if (nsel == 0)      val = acc[m][0][q];
                    else if (nsel == 1) val = acc[m][1][q];
                    else if (nsel == 2) val = acc[m][2][q];
                    else                val = acc[m][3][q];
                    label_logit[rowg] = val;
                }
            }
        }
    }
}

// ---------- per-row combine of partials -> nll ----------
__global__ void row_nll_kernel(const float* __restrict__ partial_m,
                               const float* __restrict__ partial_s,
                               const float* __restrict__ label_logit,
                               const int* __restrict__ labels,
                               float* __restrict__ nll)
{
    int row = blockIdx.x * blockDim.x + threadIdx.x;
    if (row >= N_) return;
    const float* pm = partial_m + (size_t)row * NVB;
    const float* ps = partial_s + (size_t)row * NVB;
    float mm = -INFINITY;
    for (int j = 0; j < NVB; ++j) mm = fmaxf(mm, pm[j]);
    float ss = 0.f;
    for (int j = 0; j < NVB; ++j) ss += ps[j] * expf(pm[j] - mm);
    float lse = mm + logf(ss);
    int b = row / (S_ - 1);
    int s = row - b * (S_ - 1);
    int lbl = labels[b * S_ + s + 1];
    float out = 0.f;
    if (lbl != IGNORE_INDEX) out = lse - label_logit[row];
    nll[row] = out;
}

// ---------- final mean over valid rows ----------
__global__ void final_reduce_kernel(const float* __restrict__ nll,
                                    const int* __restrict__ labels,
                                    float* __restrict__ out)
{
    __shared__ float s_sum[256];
    __shared__ float s_cnt[256];
    int tid = threadIdx.x;
    float sum = 0.f, cnt = 0.f;
    for (int row = tid; row < N_; row += 256) {
        int b = row / (S_ - 1);
        int s = row - b * (S_ - 1);
        int lbl = labels[b * S_ + s + 1];
        if (lbl != IGNORE_INDEX) { sum += nll[row]; cnt += 1.f; }
    }
    s_sum[tid] = sum; s_cnt[tid] = cnt;
    __syncthreads();
    for (int d = 128; d > 0; d >>= 1) {
        if (tid < d) { s_sum[tid] += s_sum[tid + d]; s_cnt[tid] += s_cnt[tid + d]; }
        __syncthreads();
    }
    if (tid == 0) out[0] = s_sum[0] / fmaxf(s_cnt[0], 1.f);
}

extern "C" void kernel_launch(void* const* d_in, const int* in_sizes, int n_in,
                              void* d_out, int out_size, void* d_ws, size_t ws_size,
                              hipStream_t stream) {
    const float* hs  = (const float*)d_in[0];
    const float* w   = (const float*)d_in[1];
    const int*   lbl = (const int*)d_in[2];
    float* out = (float*)d_out;

    char* ws = (char*)d_ws;
    size_t off = 0;
    unsigned short* A_bf16 = (unsigned short*)(ws + off); off += (size_t)NPAD * H_ * 2;   // 64 MB
    unsigned short* W_bf16 = (unsigned short*)(ws + off); off += (size_t)V_ * H_ * 2;     // 250 MB
    float* partial_m   = (float*)(ws + off); off += (size_t)NPAD * NVB * 4;               // 4 MB
    float* partial_s   = (float*)(ws + off); off += (size_t)NPAD * NVB * 4;               // 4 MB
    float* label_logit = (float*)(ws + off); off += (size_t)NPAD * 4;
    float* nll         = (float*)(ws + off); off += (size_t)NPAD * 4;

    {
        int total = NPAD * (H_ / 8);
        conv_hs_kernel<<<(total + 255) / 256, 256, 0, stream>>>(hs, A_bf16);
    }
    {
        int total = V_ * (H_ / 8);
        conv_w_kernel<<<(total + 255) / 256, 256, 0, stream>>>(w, W_bf16);
    }
    gemm_lse_kernel<<<NWG, 512, 0, stream>>>(A_bf16, W_bf16, lbl,
                                             partial_m, partial_s, label_logit);
    row_nll_kernel<<<(N_ + 255) / 256, 256, 0, stream>>>(partial_m, partial_s, label_logit, lbl, nll);
    final_reduce_kernel<<<1, 256, 0, stream>>>(nll, lbl, out);
}

// Round 3
// 2232.814 us; speedup vs baseline: 1.6511x; 1.0371x over previous
//
#include <hip/hip_runtime.h>
#include <hip/hip_bf16.h>
#include <math.h>

#define IGNORE_INDEX (-100)

typedef __attribute__((ext_vector_type(8))) __bf16 bf16x8;
typedef __attribute__((ext_vector_type(8))) unsigned short u16x8;
typedef __attribute__((ext_vector_type(4))) float f32x4;

static constexpr int B_ = 4, S_ = 2048, H_ = 4096, V_ = 32000;
static constexpr int N_ = B_ * (S_ - 1);      // 8188 rows after causal shift
static constexpr int NPAD = 8192;             // padded rows
static constexpr int BM = 256, BN = 256, BK = 64;
static constexpr int NVB = V_ / BN;           // 125 v-blocks
static constexpr int NRB = NPAD / BM;         // 32 row-blocks
static constexpr int NKT = H_ / BK;           // 64 K-tiles
static constexpr int NWG = NVB * NRB;         // 4000 blocks

__device__ __forceinline__ unsigned short f2bf(float f) {
    unsigned int u = __float_as_uint(f);
    unsigned int r = (u + 0x7FFFu + ((u >> 16) & 1u)) >> 16;
    return (unsigned short)r;
}

__device__ __forceinline__ bf16x8 as_bf16x8(u16x8 v) {
    return __builtin_bit_cast(bf16x8, v);
}

__device__ __forceinline__ void gload16(const unsigned short* src, unsigned short* ldst) {
    __builtin_amdgcn_global_load_lds(
        (const __attribute__((address_space(1))) unsigned int*)src,
        (__attribute__((address_space(3))) unsigned int*)ldst, 16, 0, 0);
}

// ---------- convert hidden_states (causal-shifted) to bf16, pad to NPAD rows ----------
__global__ void conv_hs_kernel(const float* __restrict__ hs, unsigned short* __restrict__ A) {
    int idx = blockIdx.x * blockDim.x + threadIdx.x;   // one thread per 8 elements
    const int W8 = H_ / 8;                             // 512
    if (idx >= NPAD * W8) return;
    int row = idx / W8;
    int h8  = (idx - row * W8) * 8;
    u16x8 out;
    if (row < N_) {
        int b = row / (S_ - 1);
        int s = row - b * (S_ - 1);
        const float* src = hs + (size_t)(b * S_ + s) * H_ + h8;
        f32x4 v0 = *(const f32x4*)(src);
        f32x4 v1 = *(const f32x4*)(src + 4);
        out[0] = f2bf(v0.x); out[1] = f2bf(v0.y); out[2] = f2bf(v0.z); out[3] = f2bf(v0.w);
        out[4] = f2bf(v1.x); out[5] = f2bf(v1.y); out[6] = f2bf(v1.z); out[7] = f2bf(v1.w);
    } else {
        out = (u16x8)0;
    }
    *(u16x8*)(A + (size_t)row * H_ + h8) = out;
}

// ---------- convert lm_head weight to bf16 ----------
__global__ void conv_w_kernel(const float* __restrict__ w, unsigned short* __restrict__ Wb) {
    int idx = blockIdx.x * blockDim.x + threadIdx.x;   // one thread per 8 elements
    const int W8 = H_ / 8;
    if (idx >= V_ * W8) return;
    int row = idx / W8;
    int h8  = (idx - row * W8) * 8;
    const float* src = w + (size_t)row * H_ + h8;
    f32x4 v0 = *(const f32x4*)(src);
    f32x4 v1 = *(const f32x4*)(src + 4);
    u16x8 out;
    out[0] = f2bf(v0.x); out[1] = f2bf(v0.y); out[2] = f2bf(v0.z); out[3] = f2bf(v0.w);
    out[4] = f2bf(v1.x); out[5] = f2bf(v1.y); out[6] = f2bf(v1.z); out[7] = f2bf(v1.w);
    *(u16x8*)(Wb + (size_t)row * H_ + h8) = out;
}

// ---------- 256x256 8-wave phase-split GEMM + fused partial logsumexp ----------
// LDS layout per buffer per matrix: logical [256 rows][64 cols] bf16, row stride 128 B.
// physical byte = logical byte ^ ((row&7)<<4)  -- 3-bit slot swizzle, involution.
// Note: swizzle touches byte bits 4..6, so the kk half-step (logical +64) is
// physical ^64, and staging source must be inverse-swizzled (same formula).
__global__ __launch_bounds__(512, 2) void gemm_lse_kernel(
        const unsigned short* __restrict__ A,   // [NPAD][H] bf16
        const unsigned short* __restrict__ Wb,  // [V][H] bf16
        const int* __restrict__ labels,         // [B][S]
        float* __restrict__ partial_m,          // [NPAD][NVB]
        float* __restrict__ partial_s,          // [NPAD][NVB]
        float* __restrict__ label_logit)        // [NPAD]
{
    __shared__ unsigned short lds[2][2][BM * BK];   // [buf][A=0/B=1], 128 KiB total

    const int tid  = threadIdx.x;
    const int lane = tid & 63;
    const int wid  = tid >> 6;
    const int wr   = wid >> 2;      // 0..1: row half (also: which A-half this wave stages)
    const int wc   = wid & 3;       // 0..3: col quarter
    const int aw   = wid & 3;       // index within A-staging group
    const int lq   = lane & 15;
    const int lr   = lane >> 4;

    // bijective XCD swizzle (NWG % 8 == 0): each XCD gets 500 consecutive tiles
    int lin = blockIdx.x;
    int swz = (lin & 7) * (NWG / 8) + (lin >> 3);
    const int rb = swz / NVB;
    const int vb = swz - rb * NVB;

    const unsigned short* Abase = A  + (size_t)rb * BM * H_;
    const unsigned short* Bbase = Wb + (size_t)vb * BN * H_;

    // ds_read physical byte offsets for kk=0 (kk=1 is offset ^ 64)
    int pA[8], pB[4];
    #pragma unroll
    for (int m = 0; m < 8; ++m) {
        int r = wr * 128 + m * 16 + lq;
        pA[m] = (r * 128 + lr * 16) ^ ((r & 7) << 4);
    }
    #pragma unroll
    for (int n = 0; n < 4; ++n) {
        int r = wc * 64 + n * 16 + lq;
        pB[n] = (r * 128 + lr * 16) ^ ((r & 7) << 4);
    }

    // staging: physical dest is linear (gload_lds writes base+lane*16);
    // per-lane global source is inverse-swizzled (same involution).
    // B: 4 slots = (half h, pass p); dest base = h*16384 + p*8192 + wid*1024
    int rowB[4], colB[4];
    #pragma unroll
    for (int s = 0; s < 4; ++s) {
        int q = (s >> 1) * 16384 + (s & 1) * 8192 + tid * 16;   // physical
        int b = q ^ (((q >> 7) & 7) << 4);                      // logical
        rowB[s] = b >> 7;
        colB[s] = (b & 127) >> 1;
    }
    // A: wave-split — waves with wr=0 stage rows 0..127, wr=1 stage 128..255; 4 passes each
    int rowA[4], colA[4];
    #pragma unroll
    for (int p = 0; p < 4; ++p) {
        int q = wr * 16384 + (aw * 4 + p) * 1024 + lane * 16;
        int b = q ^ (((q >> 7) & 7) << 4);
        rowA[p] = b >> 7;
        colA[p] = (b & 127) >> 1;
    }

    f32x4 acc[8][4] = {};

    // ---------- prologue: stage K-tile 0 into buf0 ----------
    {
        unsigned short* sA = &lds[0][0][0];
        unsigned short* sB = &lds[0][1][0];
        #pragma unroll
        for (int s = 0; s < 4; ++s)
            gload16(Bbase + (size_t)rowB[s] * H_ + colB[s],
                    (unsigned short*)((char*)sB + (s >> 1) * 16384 + (s & 1) * 8192 + wid * 1024));
        #pragma unroll
        for (int p = 0; p < 4; ++p)
            gload16(Abase + (size_t)rowA[p] * H_ + colA[p],
                    (unsigned short*)((char*)sA + wr * 16384 + (aw * 4 + p) * 1024));
    }
    asm volatile("s_waitcnt vmcnt(0)" ::: "memory");
    __builtin_amdgcn_s_barrier();

#define RD(tile, off) (*(const u16x8*)((const char*)(tile) + (off)))
#define MF(af, bf, c4) __builtin_amdgcn_mfma_f32_16x16x32_bf16(as_bf16x8(af), as_bf16x8(bf), c4, 0, 0, 0)
#define MFMA16(MO) do { \
    acc[MO+0][0]=MF(a0,b0,acc[MO+0][0]); acc[MO+0][1]=MF(a0,b1,acc[MO+0][1]); \
    acc[MO+0][2]=MF(a0,b2,acc[MO+0][2]); acc[MO+0][3]=MF(a0,b3,acc[MO+0][3]); \
    acc[MO+1][0]=MF(a1,b0,acc[MO+1][0]); acc[MO+1][1]=MF(a1,b1,acc[MO+1][1]); \
    acc[MO+1][2]=MF(a1,b2,acc[MO+1][2]); acc[MO+1][3]=MF(a1,b3,acc[MO+1][3]); \
    acc[MO+2][0]=MF(a2,b0,acc[MO+2][0]); acc[MO+2][1]=MF(a2,b1,acc[MO+2][1]); \
    acc[MO+2][2]=MF(a2,b2,acc[MO+2][2]); acc[MO+2][3]=MF(a2,b3,acc[MO+2][3]); \
    acc[MO+3][0]=MF(a3,b0,acc[MO+3][0]); acc[MO+3][1]=MF(a3,b1,acc[MO+3][1]); \
    acc[MO+3][2]=MF(a3,b2,acc[MO+3][2]); acc[MO+3][3]=MF(a3,b3,acc[MO+3][3]); \
} while (0)
#define PHASE_MID() do { \
    __builtin_amdgcn_s_barrier(); \
    asm volatile("s_waitcnt lgkmcnt(0)" ::: "memory"); \
    __builtin_amdgcn_sched_barrier(0); \
    __builtin_amdgcn_s_setprio(1); } while (0)
#define PHASE_END() do { \
    __builtin_amdgcn_s_setprio(0); \
    __builtin_amdgcn_s_barrier(); } while (0)

    for (int T = 0; T < NKT; ++T) {
        const int c = T & 1;
        const unsigned short* tA = &lds[c][0][0];
        const unsigned short* tB = &lds[c][1][0];
        unsigned short* sA = &lds[c ^ 1][0][0];
        unsigned short* sB = &lds[c ^ 1][1][0];
        const int kn = (T + 1) * BK;
        const bool pre = (T + 1 < NKT);
        u16x8 a0, a1, a2, a3, b0, b1, b2, b3;

        // ---- phase 0: stage A(T+1) (earliest: drained last-to-first cover); read A m0-3 kk0 + B kk0
        if (pre) {
            #pragma unroll
            for (int p = 0; p < 4; ++p)
                gload16(Abase + (size_t)rowA[p] * H_ + kn + colA[p],
                        (unsigned short*)((char*)sA + wr * 16384 + (aw * 4 + p) * 1024));
        }
        a0 = RD(tA, pA[0]); a1 = RD(tA, pA[1]); a2 = RD(tA, pA[2]); a3 = RD(tA, pA[3]);
        b0 = RD(tB, pB[0]); b1 = RD(tB, pB[1]); b2 = RD(tB, pB[2]); b3 = RD(tB, pB[3]);
        PHASE_MID(); MFMA16(0); PHASE_END();

        // ---- phase 1: stage B-top(T+1); read A m4-7 kk0; MFMA lower kk0
        if (pre) {
            gload16(Bbase + (size_t)rowB[0] * H_ + kn + colB[0],
                    (unsigned short*)((char*)sB + 0 * 8192 + wid * 1024));
            gload16(Bbase + (size_t)rowB[1] * H_ + kn + colB[1],
                    (unsigned short*)((char*)sB + 1 * 8192 + wid * 1024));
        }
        a0 = RD(tA, pA[4]); a1 = RD(tA, pA[5]); a2 = RD(tA, pA[6]); a3 = RD(tA, pA[7]);
        PHASE_MID(); MFMA16(4); PHASE_END();

        // ---- phase 2: stage B-bot(T+1); read A m0-3 kk1 + B kk1
        if (pre) {
            gload16(Bbase + (size_t)rowB[2] * H_ + kn + colB[2],
                    (unsigned short*)((char*)sB + 16384 + 0 * 8192 + wid * 1024));
            gload16(Bbase + (size_t)rowB[3] * H_ + kn + colB[3],
                    (unsigned short*)((char*)sB + 16384 + 1 * 8192 + wid * 1024));
        }
        a0 = RD(tA, pA[0] ^ 64); a1 = RD(tA, pA[1] ^ 64); a2 = RD(tA, pA[2] ^ 64); a3 = RD(tA, pA[3] ^ 64);
        b0 = RD(tB, pB[0] ^ 64); b1 = RD(tB, pB[1] ^ 64); b2 = RD(tB, pB[2] ^ 64); b3 = RD(tB, pB[3] ^ 64);
        PHASE_MID(); MFMA16(0); PHASE_END();

        // ---- phase 3: read A m4-7 kk1; MFMA lower kk1; drain stages for next tile
        a0 = RD(tA, pA[4] ^ 64); a1 = RD(tA, pA[5] ^ 64); a2 = RD(tA, pA[6] ^ 64); a3 = RD(tA, pA[7] ^ 64);
        PHASE_MID(); MFMA16(4);
        __builtin_amdgcn_s_setprio(0);
        asm volatile("s_waitcnt vmcnt(0)" ::: "memory");
        __builtin_amdgcn_s_barrier();
    }

    // ---------- epilogue: per-row max & sum-exp over this 256-col tile ----------
    __syncthreads();
    float* red_m = (float*)&lds[0][0][0];   // [4][256]
    float* red_s = red_m + 1024;            // [4][256]

    #pragma unroll
    for (int m = 0; m < 8; ++m) {
        #pragma unroll
        for (int q = 0; q < 4; ++q) {
            float mx = fmaxf(fmaxf(acc[m][0][q], acc[m][1][q]), fmaxf(acc[m][2][q], acc[m][3][q]));
            #pragma unroll
            for (int d = 1; d < 16; d <<= 1) mx = fmaxf(mx, __shfl_xor(mx, d, 64));
            float ss = __expf(acc[m][0][q] - mx) + __expf(acc[m][1][q] - mx)
                     + __expf(acc[m][2][q] - mx) + __expf(acc[m][3][q] - mx);
            #pragma unroll
            for (int d = 1; d < 16; d <<= 1) ss += __shfl_xor(ss, d, 64);
            if (lq == 0) {
                int rloc = wr * 128 + m * 16 + lr * 4 + q;
                red_m[wc * 256 + rloc] = mx;
                red_s[wc * 256 + rloc] = ss;
            }
        }
    }
    __syncthreads();
    if (tid < 256) {
        float m0 = red_m[tid], m1 = red_m[256 + tid], m2 = red_m[512 + tid], m3 = red_m[768 + tid];
        float s0 = red_s[tid], s1 = red_s[256 + tid], s2 = red_s[512 + tid], s3 = red_s[768 + tid];
        float mm = fmaxf(fmaxf(m0, m1), fmaxf(m2, m3));
        float ss = s0 * __expf(m0 - mm) + s1 * __expf(m1 - mm)
                 + s2 * __expf(m2 - mm) + s3 * __expf(m3 - mm);
        int rowg = rb * BM + tid;
        partial_m[(size_t)rowg * NVB + vb] = mm;
        partial_s[(size_t)rowg * NVB + vb] = ss;
    }

    // ---------- capture the label logit if it falls in this tile ----------
    #pragma unroll
    for (int m = 0; m < 8; ++m) {
        #pragma unroll
        for (int q = 0; q < 4; ++q) {
            int rowg = rb * BM + wr * 128 + m * 16 + lr * 4 + q;
            if (rowg < N_) {
                int bb = rowg / (S_ - 1);
                int s = rowg - bb * (S_ - 1);
                int lbl = labels[bb * S_ + s + 1];
                int ccol = lbl - (vb * BN + wc * 64);
                if (ccol >= 0 && ccol < 64 && (ccol & 15) == lq) {
                    int nsel = ccol >> 4;
                    float val;
                    if (nsel == 0)      val = acc[m][0][q];
                    else if (nsel == 1) val = acc[m][1][q];
                    else if (nsel == 2) val = acc[m][2][q];
                    else                val = acc[m][3][q];
                    label_logit[rowg] = val;
                }
            }
        }
    }
}

// ---------- per-row combine of partials -> nll ----------
__global__ void row_nll_kernel(const float* __restrict__ partial_m,
                               const float* __restrict__ partial_s,
                               const float* __restrict__ label_logit,
                               const int* __restrict__ labels,
                               float* __restrict__ nll)
{
    int row = blockIdx.x * blockDim.x + threadIdx.x;
    if (row >= N_) return;
    const float* pm = partial_m + (size_t)row * NVB;
    const float* ps = partial_s + (size_t)row * NVB;
    float mm = -INFINITY;
    for (int j = 0; j < NVB; ++j) mm = fmaxf(mm, pm[j]);
    float ss = 0.f;
    for (int j = 0; j < NVB; ++j) ss += ps[j] * expf(pm[j] - mm);
    float lse = mm + logf(ss);
    int b = row / (S_ - 1);
    int s = row - b * (S_ - 1);
    int lbl = labels[b * S_ + s + 1];
    float out = 0.f;
    if (lbl != IGNORE_INDEX) out = lse - label_logit[row];
    nll[row] = out;
}

// ---------- final mean over valid rows ----------
__global__ void final_reduce_kernel(const float* __restrict__ nll,
                                    const int* __restrict__ labels,
                                    float* __restrict__ out)
{
    __shared__ float s_sum[256];
    __shared__ float s_cnt[256];
    int tid = threadIdx.x;
    float sum = 0.f, cnt = 0.f;
    for (int row = tid; row < N_; row += 256) {
        int b = row / (S_ - 1);
        int s = row - b * (S_ - 1);
        int lbl = labels[b * S_ + s + 1];
        if (lbl != IGNORE_INDEX) { sum += nll[row]; cnt += 1.f; }
    }
    s_sum[tid] = sum; s_cnt[tid] = cnt;
    __syncthreads();
    for (int d = 128; d > 0; d >>= 1) {
        if (tid < d) { s_sum[tid] += s_sum[tid + d]; s_cnt[tid] += s_cnt[tid + d]; }
        __syncthreads();
    }
    if (tid == 0) out[0] = s_sum[0] / fmaxf(s_cnt[0], 1.f);
}

extern "C" void kernel_launch(void* const* d_in, const int* in_sizes, int n_in,
                              void* d_out, int out_size, void* d_ws, size_t ws_size,
                              hipStream_t stream) {
    const float* hs  = (const float*)d_in[0];
    const float* w   = (const float*)d_in[1];
    const int*   lbl = (const int*)d_in[2];
    float* out = (float*)d_out;

    char* ws = (char*)d_ws;
    size_t off = 0;
    unsigned short* A_bf16 = (unsigned short*)(ws + off); off += (size_t)NPAD * H_ * 2;   // 64 MB
    unsigned short* W_bf16 = (unsigned short*)(ws + off); off += (size_t)V_ * H_ * 2;     // 250 MB
    float* partial_m   = (float*)(ws + off); off += (size_t)NPAD * NVB * 4;               // 4 MB
    float* partial_s   = (float*)(ws + off); off += (size_t)NPAD * NVB * 4;               // 4 MB
    float* label_logit = (float*)(ws + off); off += (size_t)NPAD * 4;
    float* nll         = (float*)(ws + off); off += (size_t)NPAD * 4;

    {
        int total = NPAD * (H_ / 8);
        conv_hs_kernel<<<(total + 255) / 256, 256, 0, stream>>>(hs, A_bf16);
    }
    {
        int total = V_ * (H_ / 8);
        conv_w_kernel<<<(total + 255) / 256, 256, 0, stream>>>(w, W_bf16);
    }
    gemm_lse_kernel<<<NWG, 512, 0, stream>>>(A_bf16, W_bf16, lbl,
                                             partial_m, partial_s, label_logit);
    row_nll_kernel<<<(N_ + 255) / 256, 256, 0, stream>>>(partial_m, partial_s, label_logit, lbl, nll);
    final_reduce_kernel<<<1, 256, 0, stream>>>(nll, lbl, out);
}